// Round 1
// 465.439 us; speedup vs baseline: 1.0674x; 1.0674x over previous
//
#include <hip/hip_runtime.h>

// MaskedLightAdaIN, fused single-pass.
// x [16,64,256,256] f32, mask [16,1,256,256] f32.
// One block (1024 threads) per (b,c) slice of 65536 elems.
// Phase 1: each thread loads its 16 float4 of x into REGISTERS while
//          accumulating {cnt_fg, sum_fg, sumsq_fg, sum_tot, sumsq_tot};
//          fg predicate packed into a 64-bit register bitmask.
// Reduce:  64-lane butterfly + LDS across 16 waves; thread 0 derives
//          A = sig_fg/(sig_bg+EPS), mu_bg, mu_fg; broadcast via LDS.
// Phase 2: apply from registers, store. x and mask each touch HBM ONCE:
//          traffic 256r + 256w + mask vs. 770 MiB for the 2-pass version.

#define HW     65536          // 256*256
#define HW4    16384          // HW/4
#define NSLICE 1024           // 16*64
#define TPB    1024
#define ITERS  16             // HW4 / TPB
#define NXCD   8

__global__ __launch_bounds__(TPB) void fused_adain_kernel(
    const float* __restrict__ x, const float* __restrict__ mask,
    float* __restrict__ out) {
  // XCD-bijective swizzle (1024 % 8 == 0): XCD k handles contiguous slices
  // [k*128, (k+1)*128) = 2 whole batches -> mask slice fetched once per XCD.
  const int slice = (blockIdx.x % NXCD) * (NSLICE / NXCD) + blockIdx.x / NXCD;
  const int b = slice >> 6;

  const float4* __restrict__ x4 = (const float4*)(x + (size_t)slice * HW);
  const float4* __restrict__ m4 = (const float4*)(mask + (size_t)b * HW);
  float4* __restrict__ o4 = (float4*)(out + (size_t)slice * HW);

  float4 xv[ITERS];                 // 64 VGPRs: the thread's chunk of x
  unsigned fgb[2] = {0u, 0u};       // 64 fg bits (4 per iter * 16 iters)
  float cnt = 0.f, sf = 0.f, s2f = 0.f, st = 0.f, s2t = 0.f;

#pragma unroll
  for (int it = 0; it < ITERS; ++it) {
    const int i = threadIdx.x + it * TPB;     // coalesced: lane-consecutive
    xv[it] = x4[i];
    float4 mv = m4[i];
    const float* xe = (const float*)&xv[it];
    const float* me = (const float*)&mv;
#pragma unroll
    for (int k = 0; k < 4; ++k) {
      float xk = xe[k];
      float x2 = xk * xk;
      bool fg = me[k] >= 0.5f;
      st  += xk;
      s2t += x2;
      cnt += fg ? 1.f : 0.f;
      sf  += fg ? xk : 0.f;
      s2f += fg ? x2 : 0.f;
      fgb[it >> 3] |= (unsigned)fg << ((it & 7) * 4 + k);  // static shifts
    }
  }

  // 64-lane butterfly reduction
#pragma unroll
  for (int off = 32; off > 0; off >>= 1) {
    cnt += __shfl_down(cnt, off);
    sf  += __shfl_down(sf,  off);
    s2f += __shfl_down(s2f, off);
    st  += __shfl_down(st,  off);
    s2t += __shfl_down(s2t, off);
  }

  __shared__ float red[16][5];
  __shared__ float bc[3];
  const int wave = threadIdx.x >> 6;
  const int lane = threadIdx.x & 63;
  if (lane == 0) {
    red[wave][0] = cnt; red[wave][1] = sf; red[wave][2] = s2f;
    red[wave][3] = st;  red[wave][4] = s2t;
  }
  __syncthreads();

  if (threadIdx.x == 0) {
    float tcnt = 0.f, tsf = 0.f, ts2f = 0.f, tst = 0.f, ts2t = 0.f;
#pragma unroll
    for (int w = 0; w < 16; ++w) {
      tcnt += red[w][0]; tsf += red[w][1]; ts2f += red[w][2];
      tst  += red[w][3]; ts2t += red[w][4];
    }
    float n_fg = tcnt;
    float n_bg = (float)HW - tcnt;
    float s_bg  = tst  - tsf;
    float s2_bg = ts2t - ts2f;

    float mu_fg  = tsf / fmaxf(n_fg, 1.f);
    float var_fg = fmaxf((ts2f - n_fg * mu_fg * mu_fg) / fmaxf(n_fg - 1.f, 1.f), 0.f);
    float sig_fg = sqrtf(var_fg);

    float mu_bg  = s_bg / fmaxf(n_bg, 1.f);
    float var_bg = fmaxf((s2_bg - n_bg * mu_bg * mu_bg) / fmaxf(n_bg - 1.f, 1.f), 0.f);
    float sig_bg = sqrtf(var_bg);

    bc[0] = sig_fg / (sig_bg + 1e-8f);   // A
    bc[1] = mu_bg;
    bc[2] = mu_fg;
  }
  __syncthreads();

  const float A     = bc[0];
  const float mu_bg = bc[1];
  const float mu_fg = bc[2];

  // Phase 2: apply from registers, stream out. No global re-reads.
#pragma unroll
  for (int it = 0; it < ITERS; ++it) {
    const int i = threadIdx.x + it * TPB;
    float4 ov;
    float* oe = (float*)&ov;
    const float* xe = (const float*)&xv[it];
#pragma unroll
    for (int k = 0; k < 4; ++k) {
      float xk = xe[k];
      float h = fmaf(xk - mu_bg, A, mu_fg);
      bool fg = (fgb[it >> 3] >> ((it & 7) * 4 + k)) & 1u;
      oe[k] = fg ? xk : h;
    }
    o4[i] = ov;
  }
}

extern "C" void kernel_launch(void* const* d_in, const int* in_sizes, int n_in,
                              void* d_out, int out_size, void* d_ws, size_t ws_size,
                              hipStream_t stream) {
  const float* x = (const float*)d_in[0];
  const float* mask = (const float*)d_in[1];
  float* out = (float*)d_out;
  (void)d_ws; (void)ws_size;

  fused_adain_kernel<<<NSLICE, TPB, 0, stream>>>(x, mask, out);
}